// Round 1
// baseline (4166.529 us; speedup 1.0000x reference)
//
#include <hip/hip_runtime.h>
#include <hip/hip_bf16.h>

#define D 128
#define NNODES 16384
#define NEDGES 262144
#define NBATCH 2
#define NS 4

// ---------------------------------------------------------------- edge kernel
#define TILE_E 16

__global__ __launch_bounds__(256)
void edge_kernel(const float* __restrict__ V, const float* __restrict__ E,
                 const int* __restrict__ edges,
                 const float* __restrict__ We1, const float* __restrict__ be1,
                 const float* __restrict__ We2, const float* __restrict__ be2,
                 float* __restrict__ m0sum, float* __restrict__ m1sum,
                 float* __restrict__ c0, float* __restrict__ c1)
{
    __shared__ float inpt[TILE_E][388];   // 384 + pad(4) -> conflict-free e-broadcast
    __shared__ float hid[TILE_E][132];    // 128 + pad(4)
    __shared__ int   eidx[TILE_E][2];

    const int t = threadIdx.x;
    const long long eflat0 = (long long)blockIdx.x * TILE_E;  // flat over BS*NE
    const int b  = (int)(eflat0 / NEDGES);
    const int e0 = (int)(eflat0 % NEDGES);

    if (t < TILE_E * 2) {
        eidx[t >> 1][t & 1] =
            edges[((long long)b * NEDGES + e0 + (t >> 1)) * 2 + (t & 1)];
    }
    __syncthreads();

    // gather [sender | receiver | E] rows into LDS (f32)
    for (int i = t; i < TILE_E * 3 * 32; i += 256) {
        int c4  = i & 31;          // float4 index within 128-wide part
        int row = i >> 5;          // 0..47
        int e    = row / 3;
        int part = row - e * 3;
        const float* src;
        if (part == 0)      src = V + ((long long)b * NNODES + eidx[e][0]) * D;
        else if (part == 1) src = V + ((long long)b * NNODES + eidx[e][1]) * D;
        else                src = E + ((long long)b * NEDGES + e0 + e) * D;
        float4 v = *(const float4*)(src + c4 * 4);
        *(float4*)(&inpt[e][part * 128 + c4 * 4]) = v;
    }
    __syncthreads();

    const int j0 = (t & 15) * 8;   // output-feature group
    const int e  = t >> 4;         // edge within tile

    // hidden = silu(x @ We1 + be1)
    float acc[8];
    #pragma unroll
    for (int i = 0; i < 8; ++i) acc[i] = be1[j0 + i];
    #pragma unroll 4
    for (int k = 0; k < 384; ++k) {
        float x = inpt[e][k];
        float4 w0 = *(const float4*)(We1 + (long long)k * 128 + j0);
        float4 w1 = *(const float4*)(We1 + (long long)k * 128 + j0 + 4);
        acc[0] = fmaf(x, w0.x, acc[0]);
        acc[1] = fmaf(x, w0.y, acc[1]);
        acc[2] = fmaf(x, w0.z, acc[2]);
        acc[3] = fmaf(x, w0.w, acc[3]);
        acc[4] = fmaf(x, w1.x, acc[4]);
        acc[5] = fmaf(x, w1.y, acc[5]);
        acc[6] = fmaf(x, w1.z, acc[6]);
        acc[7] = fmaf(x, w1.w, acc[7]);
    }
    #pragma unroll
    for (int i = 0; i < 8; ++i) {
        float a = acc[i];
        hid[e][j0 + i] = a / (1.f + __expf(-a));   // silu
    }
    __syncthreads();

    // emb = hid @ We2 + be2
    float acc2[8];
    #pragma unroll
    for (int i = 0; i < 8; ++i) acc2[i] = be2[j0 + i];
    #pragma unroll 4
    for (int k = 0; k < 128; ++k) {
        float x = hid[e][k];
        float4 w0 = *(const float4*)(We2 + k * 128 + j0);
        float4 w1 = *(const float4*)(We2 + k * 128 + j0 + 4);
        acc2[0] = fmaf(x, w0.x, acc2[0]);
        acc2[1] = fmaf(x, w0.y, acc2[1]);
        acc2[2] = fmaf(x, w0.z, acc2[2]);
        acc2[3] = fmaf(x, w0.w, acc2[3]);
        acc2[4] = fmaf(x, w1.x, acc2[4]);
        acc2[5] = fmaf(x, w1.y, acc2[5]);
        acc2[6] = fmaf(x, w1.z, acc2[6]);
        acc2[7] = fmaf(x, w1.w, acc2[7]);
    }

    // scatter: first 64 feats -> m0sum[sender], last 64 -> m1sum[receiver]
    const int snd = eidx[e][0], rcv = eidx[e][1];
    if (j0 < 64) {
        float* dst = m0sum + ((long long)b * NNODES + snd) * 64 + j0;
        #pragma unroll
        for (int i = 0; i < 8; ++i) atomicAdd(dst + i, acc2[i]);
    } else {
        float* dst = m1sum + ((long long)b * NNODES + rcv) * 64 + (j0 - 64);
        #pragma unroll
        for (int i = 0; i < 8; ++i) atomicAdd(dst + i, acc2[i]);
    }
    if (t < TILE_E) {
        atomicAdd(&c0[b * NNODES + eidx[t][0]], 1.f);
        atomicAdd(&c1[b * NNODES + eidx[t][1]], 1.f);
    }
}

// ---------------------------------------------------------------- node kernel
#define TILE_N 16

__global__ __launch_bounds__(256)
void node_kernel(const float* __restrict__ V,
                 const float* __restrict__ m0sum, const float* __restrict__ m1sum,
                 const float* __restrict__ c0, const float* __restrict__ c1,
                 const float* __restrict__ Wn1, const float* __restrict__ bn1,
                 const float* __restrict__ Wn2, const float* __restrict__ bn2,
                 float* __restrict__ node_emb)
{
    __shared__ float inpt[TILE_N][260];   // 256 + pad(4)
    __shared__ float hid[TILE_N][132];

    const int t = threadIdx.x;
    const int nflat0 = blockIdx.x * TILE_N;

    // load [V | m0 | m1] (with mean division) into LDS
    for (int i = t; i < TILE_N * 64; i += 256) {
        int c4 = i & 63;
        int n  = i >> 6;
        long long node = (long long)nflat0 + n;    // flat over BS*N
        float4 v;
        int off;
        if (c4 < 32) {
            v = *(const float4*)(V + node * 128 + c4 * 4);
            off = c4 * 4;
        } else if (c4 < 48) {
            v = *(const float4*)(m0sum + node * 64 + (c4 - 32) * 4);
            float inv = 1.f / fmaxf(c0[node], 1.f);
            v.x *= inv; v.y *= inv; v.z *= inv; v.w *= inv;
            off = 128 + (c4 - 32) * 4;
        } else {
            v = *(const float4*)(m1sum + node * 64 + (c4 - 48) * 4);
            float inv = 1.f / fmaxf(c1[node], 1.f);
            v.x *= inv; v.y *= inv; v.z *= inv; v.w *= inv;
            off = 192 + (c4 - 48) * 4;
        }
        *(float4*)(&inpt[n][off]) = v;
    }
    __syncthreads();

    const int j0 = (t & 15) * 8;
    const int n  = t >> 4;

    float acc[8];
    #pragma unroll
    for (int i = 0; i < 8; ++i) acc[i] = bn1[j0 + i];
    #pragma unroll 4
    for (int k = 0; k < 256; ++k) {
        float x = inpt[n][k];
        float4 w0 = *(const float4*)(Wn1 + (long long)k * 128 + j0);
        float4 w1 = *(const float4*)(Wn1 + (long long)k * 128 + j0 + 4);
        acc[0] = fmaf(x, w0.x, acc[0]);
        acc[1] = fmaf(x, w0.y, acc[1]);
        acc[2] = fmaf(x, w0.z, acc[2]);
        acc[3] = fmaf(x, w0.w, acc[3]);
        acc[4] = fmaf(x, w1.x, acc[4]);
        acc[5] = fmaf(x, w1.y, acc[5]);
        acc[6] = fmaf(x, w1.z, acc[6]);
        acc[7] = fmaf(x, w1.w, acc[7]);
    }
    #pragma unroll
    for (int i = 0; i < 8; ++i) {
        float a = acc[i];
        hid[n][j0 + i] = a / (1.f + __expf(-a));
    }
    __syncthreads();

    float acc2[8];
    #pragma unroll
    for (int i = 0; i < 8; ++i) acc2[i] = bn2[j0 + i];
    #pragma unroll 4
    for (int k = 0; k < 128; ++k) {
        float x = hid[n][k];
        float4 w0 = *(const float4*)(Wn2 + k * 128 + j0);
        float4 w1 = *(const float4*)(Wn2 + k * 128 + j0 + 4);
        acc2[0] = fmaf(x, w0.x, acc2[0]);
        acc2[1] = fmaf(x, w0.y, acc2[1]);
        acc2[2] = fmaf(x, w0.z, acc2[2]);
        acc2[3] = fmaf(x, w0.w, acc2[3]);
        acc2[4] = fmaf(x, w1.x, acc2[4]);
        acc2[5] = fmaf(x, w1.y, acc2[5]);
        acc2[6] = fmaf(x, w1.z, acc2[6]);
        acc2[7] = fmaf(x, w1.w, acc2[7]);
    }
    long long node = (long long)nflat0 + n;
    #pragma unroll
    for (int i = 0; i < 8; ++i) node_emb[node * 128 + j0 + i] = acc2[i];
}

// ------------------------------------------------------------ attention kernel
__global__ __launch_bounds__(256)
void attn_kernel(const float* __restrict__ blocks, const float* __restrict__ node_emb,
                 const float* __restrict__ w_attn, const float* __restrict__ rms_w,
                 float* __restrict__ out)
{
    const int t    = threadIdx.x;
    const int wave = t >> 6;
    const int lane = t & 63;
    const long long node = (long long)blockIdx.x * 4 + wave;  // flat over BS*N
    const int d0 = lane * 2;

    float2 wa = *(const float2*)(w_attn + d0);
    float2 rw = *(const float2*)(rms_w + d0);

    float xs[5][2];
    float lg[5];
    #pragma unroll
    for (int s = 0; s < 5; ++s) {
        const float* src = (s < 4)
            ? (blocks + ((long long)s * NBATCH * NNODES + node) * 128)
            : (node_emb + node * 128);
        float2 x = *(const float2*)(src + d0);
        xs[s][0] = x.x; xs[s][1] = x.y;
        float ss = x.x * x.x + x.y * x.y;
        float wv = wa.x * rw.x * x.x + wa.y * rw.y * x.y;
        #pragma unroll
        for (int m = 1; m < 64; m <<= 1) {
            ss += __shfl_xor(ss, m);
            wv += __shfl_xor(wv, m);
        }
        lg[s] = wv * rsqrtf(ss * (1.f / 128.f) + 1e-6f);
    }

    float mx = lg[0];
    #pragma unroll
    for (int s = 1; s < 5; ++s) mx = fmaxf(mx, lg[s]);
    float ex[5], sum = 0.f;
    #pragma unroll
    for (int s = 0; s < 5; ++s) { ex[s] = __expf(lg[s] - mx); sum += ex[s]; }
    float inv = 1.f / sum;

    float h0 = 0.f, h1 = 0.f;
    #pragma unroll
    for (int s = 0; s < 5; ++s) {
        float a = ex[s] * inv;
        h0 = fmaf(a, xs[s][0], h0);
        h1 = fmaf(a, xs[s][1], h1);
    }
    *(float2*)(out + node * 128 + d0) = make_float2(h0, h1);
}

// ------------------------------------------------------------------- launcher
extern "C" void kernel_launch(void* const* d_in, const int* in_sizes, int n_in,
                              void* d_out, int out_size, void* d_ws, size_t ws_size,
                              hipStream_t stream)
{
    const float* V      = (const float*)d_in[0];
    const float* E      = (const float*)d_in[1];
    const float* blocks = (const float*)d_in[2];
    const float* We1    = (const float*)d_in[3];
    const float* be1    = (const float*)d_in[4];
    const float* We2    = (const float*)d_in[5];
    const float* be2    = (const float*)d_in[6];
    const float* Wn1    = (const float*)d_in[7];
    const float* bn1    = (const float*)d_in[8];
    const float* Wn2    = (const float*)d_in[9];
    const float* bn2    = (const float*)d_in[10];
    const float* w_attn = (const float*)d_in[11];
    const float* rms_w  = (const float*)d_in[12];
    const int*   edges  = (const int*)d_in[13];
    float* out = (float*)d_out;

    float* ws = (float*)d_ws;
    float* m0sum    = ws;                         // BS*N*64 = 2,097,152
    float* m1sum    = m0sum + 2097152;            // 2,097,152
    float* c0       = m1sum + 2097152;            // 32,768
    float* c1       = c0 + 32768;                 // 32,768
    float* node_emb = c1 + 32768;                 // 4,194,304

    // zero accumulators (m0sum, m1sum, c0, c1)
    hipMemsetAsync(d_ws, 0, (size_t)(2097152 * 2 + 32768 * 2) * sizeof(float), stream);

    // 1) edge MLP + scatter
    {
        dim3 grid((NBATCH * NEDGES) / TILE_E);
        edge_kernel<<<grid, 256, 0, stream>>>(V, E, edges, We1, be1, We2, be2,
                                              m0sum, m1sum, c0, c1);
    }
    // 2) node MLP
    {
        dim3 grid((NBATCH * NNODES) / TILE_N);
        node_kernel<<<grid, 256, 0, stream>>>(V, m0sum, m1sum, c0, c1,
                                              Wn1, bn1, Wn2, bn2, node_emb);
    }
    // 3) depth attention
    {
        dim3 grid((NBATCH * NNODES) / 4);
        attn_kernel<<<grid, 256, 0, stream>>>(blocks, node_emb, w_attn, rms_w, out);
    }
}

// Round 2
// 616.116 us; speedup vs baseline: 6.7626x; 6.7626x over previous
//
#include <hip/hip_runtime.h>
#include <hip/hip_bf16.h>

#define D 128
#define NNODES 16384
#define NEDGES 262144
#define NBATCH 2
#define TE 64

typedef __attribute__((ext_vector_type(8))) short bf16x8;
typedef __attribute__((ext_vector_type(4))) float f32x4;

__device__ __forceinline__ unsigned short f2bf(float f) {
    unsigned int u = __float_as_uint(f);
    unsigned int r = (u + 0x7fffu + ((u >> 16) & 1u)) >> 16;
    return (unsigned short)r;
}

// --------------------------------------------------------------- weight prep
// Transposed bf16 copies: dst[n*K + k] = bf16(src[k*128 + n]); all have 128 cols.
__global__ __launch_bounds__(256)
void prep_weights(const float* __restrict__ We1, const float* __restrict__ We2,
                  const float* __restrict__ Wn1, const float* __restrict__ Wn2,
                  unsigned short* __restrict__ w)
{
    int id = blockIdx.x * 256 + threadIdx.x;   // 114688 total
    const float* src; int K; unsigned short* dst; int r;
    if (id < 49152)      { src = We1; K = 384; dst = w;         r = id; }
    else if (id < 65536) { src = We2; K = 128; dst = w + 49152; r = id - 49152; }
    else if (id < 98304) { src = Wn1; K = 256; dst = w + 65536; r = id - 65536; }
    else                 { src = Wn2; K = 128; dst = w + 98304; r = id - 98304; }
    int n = r / K, k = r - n * K;
    dst[r] = f2bf(src[k * 128 + n]);
}

// ---------------------------------------------------------------- edge kernel
// 64 edges/block, 4 waves (2x2 of 32x64 tiles). MFMA 16x16x32 bf16.
__global__ __launch_bounds__(256)
void edge_kernel(const float* __restrict__ V, const float* __restrict__ E,
                 const int* __restrict__ edges,
                 const unsigned short* __restrict__ we1t, const float* __restrict__ be1,
                 const unsigned short* __restrict__ we2t, const float* __restrict__ be2,
                 float* __restrict__ m0sum, float* __restrict__ m1sum,
                 float* __restrict__ c0, float* __restrict__ c1)
{
    __shared__ unsigned short smem[TE * 392];   // A tile [64][392]; reused as H [64][136]
    __shared__ int eidx[TE][2];

    const int t    = threadIdx.x;
    const int lane = t & 63;
    const int wave = t >> 6;
    const int wr   = wave >> 1;          // edge-row block (32)
    const int wc   = wave & 1;           // out-col block (64) ; wc=0 -> m0, wc=1 -> m1
    const int l15  = lane & 15;
    const int l4   = lane >> 4;

    const long long eflat0 = (long long)blockIdx.x * TE;
    const int b  = (int)(eflat0 / NEDGES);
    const int e0 = (int)(eflat0 % NEDGES);

    if (t < TE * 2) {
        eidx[t >> 1][t & 1] =
            edges[((long long)b * NEDGES + e0 + (t >> 1)) * 2 + (t & 1)];
    }
    __syncthreads();

    // gather [snd|rcv|E] rows -> bf16 LDS tile [64][392] (pad 8)
    for (int i = t; i < TE * 96; i += 256) {
        int c4 = i % 96;
        int e  = i / 96;
        int part = c4 >> 5;
        int w32  = c4 & 31;
        const float* src;
        if (part == 0)      src = V + ((long long)b * NNODES + eidx[e][0]) * D;
        else if (part == 1) src = V + ((long long)b * NNODES + eidx[e][1]) * D;
        else                src = E + ((long long)b * NEDGES + e0 + e) * D;
        float4 v = *(const float4*)(src + w32 * 4);
        unsigned int lo = f2bf(v.x) | ((unsigned int)f2bf(v.y) << 16);
        unsigned int hi = f2bf(v.z) | ((unsigned int)f2bf(v.w) << 16);
        uint2 p; p.x = lo; p.y = hi;
        *(uint2*)(&smem[e * 392 + c4 * 4]) = p;
    }
    __syncthreads();

    // ---- layer 1: [64x384] @ [384x128] ----
    f32x4 acc[2][4] = {};
    {
        const unsigned short* arow = &smem[(wr * 32 + l15) * 392 + l4 * 8];
        const unsigned short* bb0  = we1t + (wc * 64 + l15) * 384 + l4 * 8;
        for (int ks = 0; ks < 12; ++ks) {
            bf16x8 a0 = *(const bf16x8*)(arow + ks * 32);
            bf16x8 a1 = *(const bf16x8*)(arow + 16 * 392 + ks * 32);
            #pragma unroll
            for (int n = 0; n < 4; ++n) {
                bf16x8 bb = *(const bf16x8*)(bb0 + n * 16 * 384 + ks * 32);
                acc[0][n] = __builtin_amdgcn_mfma_f32_16x16x32_bf16(a0, bb, acc[0][n], 0, 0, 0);
                acc[1][n] = __builtin_amdgcn_mfma_f32_16x16x32_bf16(a1, bb, acc[1][n], 0, 0, 0);
            }
        }
    }
    __syncthreads();   // everyone done reading A before H overwrites smem

    // bias + silu -> H tile [64][136] bf16 (reusing smem)
    #pragma unroll
    for (int n = 0; n < 4; ++n) {
        int col = wc * 64 + n * 16 + l15;
        float bias = be1[col];
        #pragma unroll
        for (int m = 0; m < 2; ++m) {
            #pragma unroll
            for (int i = 0; i < 4; ++i) {
                int row = wr * 32 + m * 16 + l4 * 4 + i;
                float a = acc[m][n][i] + bias;
                smem[row * 136 + col] = f2bf(a / (1.f + __expf(-a)));
            }
        }
    }
    __syncthreads();

    // ---- layer 2: [64x128] @ [128x128] ----
    f32x4 acc2[2][4] = {};
    {
        const unsigned short* hrow = &smem[(wr * 32 + l15) * 136 + l4 * 8];
        const unsigned short* bb0  = we2t + (wc * 64 + l15) * 128 + l4 * 8;
        #pragma unroll
        for (int ks = 0; ks < 4; ++ks) {
            bf16x8 a0 = *(const bf16x8*)(hrow + ks * 32);
            bf16x8 a1 = *(const bf16x8*)(hrow + 16 * 136 + ks * 32);
            #pragma unroll
            for (int n = 0; n < 4; ++n) {
                bf16x8 bb = *(const bf16x8*)(bb0 + n * 16 * 128 + ks * 32);
                acc2[0][n] = __builtin_amdgcn_mfma_f32_16x16x32_bf16(a0, bb, acc2[0][n], 0, 0, 0);
                acc2[1][n] = __builtin_amdgcn_mfma_f32_16x16x32_bf16(a1, bb, acc2[1][n], 0, 0, 0);
            }
        }
    }

    // scatter: wc=0 -> cols 0..63 to m0sum[snd]; wc=1 -> cols 64..127 to m1sum[rcv]
    float* dst_arr = wc ? m1sum : m0sum;
    #pragma unroll
    for (int n = 0; n < 4; ++n) {
        int colh = n * 16 + l15;
        float bias = be2[wc * 64 + colh];
        #pragma unroll
        for (int m = 0; m < 2; ++m) {
            #pragma unroll
            for (int i = 0; i < 4; ++i) {
                int erow = wr * 32 + m * 16 + l4 * 4 + i;
                int node = eidx[erow][wc];
                atomicAdd(dst_arr + ((long long)b * NNODES + node) * 64 + colh,
                          acc2[m][n][i] + bias);
            }
        }
    }
    if (t < TE)          atomicAdd(&c0[b * NNODES + eidx[t][0]], 1.f);
    else if (t < 2 * TE) atomicAdd(&c1[b * NNODES + eidx[t - TE][1]], 1.f);
}

// ---------------------------------------------------------------- node kernel
__global__ __launch_bounds__(256)
void node_kernel(const float* __restrict__ V,
                 const float* __restrict__ m0sum, const float* __restrict__ m1sum,
                 const float* __restrict__ c0, const float* __restrict__ c1,
                 const unsigned short* __restrict__ wn1t, const float* __restrict__ bn1,
                 const unsigned short* __restrict__ wn2t, const float* __restrict__ bn2,
                 float* __restrict__ node_emb)
{
    __shared__ unsigned short smem[TE * 264];   // A [64][264]; reused as H [64][136]

    const int t    = threadIdx.x;
    const int lane = t & 63;
    const int wave = t >> 6;
    const int wr   = wave >> 1;
    const int wc   = wave & 1;
    const int l15  = lane & 15;
    const int l4   = lane >> 4;

    const long long nflat0 = (long long)blockIdx.x * TE;

    // assemble [V | m0/c0 | m1/c1] -> bf16 LDS [64][264]
    for (int i = t; i < TE * 64; i += 256) {
        int c4 = i & 63;
        int n  = i >> 6;
        long long node = nflat0 + n;
        float4 v; int off;
        if (c4 < 32) {
            v = *(const float4*)(V + node * 128 + c4 * 4);
            off = c4 * 4;
        } else if (c4 < 48) {
            v = *(const float4*)(m0sum + node * 64 + (c4 - 32) * 4);
            float inv = 1.f / fmaxf(c0[node], 1.f);
            v.x *= inv; v.y *= inv; v.z *= inv; v.w *= inv;
            off = 128 + (c4 - 32) * 4;
        } else {
            v = *(const float4*)(m1sum + node * 64 + (c4 - 48) * 4);
            float inv = 1.f / fmaxf(c1[node], 1.f);
            v.x *= inv; v.y *= inv; v.z *= inv; v.w *= inv;
            off = 192 + (c4 - 48) * 4;
        }
        unsigned int lo = f2bf(v.x) | ((unsigned int)f2bf(v.y) << 16);
        unsigned int hi = f2bf(v.z) | ((unsigned int)f2bf(v.w) << 16);
        uint2 p; p.x = lo; p.y = hi;
        *(uint2*)(&smem[n * 264 + c4 * 4]) = p;
    }
    __syncthreads();

    // ---- layer 1: [64x256] @ [256x128] ----
    f32x4 acc[2][4] = {};
    {
        const unsigned short* arow = &smem[(wr * 32 + l15) * 264 + l4 * 8];
        const unsigned short* bb0  = wn1t + (wc * 64 + l15) * 256 + l4 * 8;
        for (int ks = 0; ks < 8; ++ks) {
            bf16x8 a0 = *(const bf16x8*)(arow + ks * 32);
            bf16x8 a1 = *(const bf16x8*)(arow + 16 * 264 + ks * 32);
            #pragma unroll
            for (int n = 0; n < 4; ++n) {
                bf16x8 bb = *(const bf16x8*)(bb0 + n * 16 * 256 + ks * 32);
                acc[0][n] = __builtin_amdgcn_mfma_f32_16x16x32_bf16(a0, bb, acc[0][n], 0, 0, 0);
                acc[1][n] = __builtin_amdgcn_mfma_f32_16x16x32_bf16(a1, bb, acc[1][n], 0, 0, 0);
            }
        }
    }
    __syncthreads();

    #pragma unroll
    for (int n = 0; n < 4; ++n) {
        int col = wc * 64 + n * 16 + l15;
        float bias = bn1[col];
        #pragma unroll
        for (int m = 0; m < 2; ++m) {
            #pragma unroll
            for (int i = 0; i < 4; ++i) {
                int row = wr * 32 + m * 16 + l4 * 4 + i;
                float a = acc[m][n][i] + bias;
                smem[row * 136 + col] = f2bf(a / (1.f + __expf(-a)));
            }
        }
    }
    __syncthreads();

    // ---- layer 2: [64x128] @ [128x128] ----
    f32x4 acc2[2][4] = {};
    {
        const unsigned short* hrow = &smem[(wr * 32 + l15) * 136 + l4 * 8];
        const unsigned short* bb0  = wn2t + (wc * 64 + l15) * 128 + l4 * 8;
        #pragma unroll
        for (int ks = 0; ks < 4; ++ks) {
            bf16x8 a0 = *(const bf16x8*)(hrow + ks * 32);
            bf16x8 a1 = *(const bf16x8*)(hrow + 16 * 136 + ks * 32);
            #pragma unroll
            for (int n = 0; n < 4; ++n) {
                bf16x8 bb = *(const bf16x8*)(bb0 + n * 16 * 128 + ks * 32);
                acc2[0][n] = __builtin_amdgcn_mfma_f32_16x16x32_bf16(a0, bb, acc2[0][n], 0, 0, 0);
                acc2[1][n] = __builtin_amdgcn_mfma_f32_16x16x32_bf16(a1, bb, acc2[1][n], 0, 0, 0);
            }
        }
    }

    #pragma unroll
    for (int n = 0; n < 4; ++n) {
        int col = wc * 64 + n * 16 + l15;
        float bias = bn2[col];
        #pragma unroll
        for (int m = 0; m < 2; ++m) {
            #pragma unroll
            for (int i = 0; i < 4; ++i) {
                long long row = nflat0 + wr * 32 + m * 16 + l4 * 4 + i;
                node_emb[row * 128 + col] = acc2[m][n][i] + bias;
            }
        }
    }
}

// ------------------------------------------------------------ attention kernel
__global__ __launch_bounds__(256)
void attn_kernel(const float* __restrict__ blocks, const float* __restrict__ node_emb,
                 const float* __restrict__ w_attn, const float* __restrict__ rms_w,
                 float* __restrict__ out)
{
    const int t    = threadIdx.x;
    const int wave = t >> 6;
    const int lane = t & 63;
    const long long node = (long long)blockIdx.x * 4 + wave;
    const int d0 = lane * 2;

    float2 wa = *(const float2*)(w_attn + d0);
    float2 rw = *(const float2*)(rms_w + d0);

    float xs[5][2];
    float lg[5];
    #pragma unroll
    for (int s = 0; s < 5; ++s) {
        const float* src = (s < 4)
            ? (blocks + ((long long)s * NBATCH * NNODES + node) * 128)
            : (node_emb + node * 128);
        float2 x = *(const float2*)(src + d0);
        xs[s][0] = x.x; xs[s][1] = x.y;
        float ss = x.x * x.x + x.y * x.y;
        float wv = wa.x * rw.x * x.x + wa.y * rw.y * x.y;
        #pragma unroll
        for (int m = 1; m < 64; m <<= 1) {
            ss += __shfl_xor(ss, m);
            wv += __shfl_xor(wv, m);
        }
        lg[s] = wv * rsqrtf(ss * (1.f / 128.f) + 1e-6f);
    }

    float mx = lg[0];
    #pragma unroll
    for (int s = 1; s < 5; ++s) mx = fmaxf(mx, lg[s]);
    float ex[5], sum = 0.f;
    #pragma unroll
    for (int s = 0; s < 5; ++s) { ex[s] = __expf(lg[s] - mx); sum += ex[s]; }
    float inv = 1.f / sum;

    float h0 = 0.f, h1 = 0.f;
    #pragma unroll
    for (int s = 0; s < 5; ++s) {
        float a = ex[s] * inv;
        h0 = fmaf(a, xs[s][0], h0);
        h1 = fmaf(a, xs[s][1], h1);
    }
    *(float2*)(out + node * 128 + d0) = make_float2(h0, h1);
}

// ------------------------------------------------------------------- launcher
extern "C" void kernel_launch(void* const* d_in, const int* in_sizes, int n_in,
                              void* d_out, int out_size, void* d_ws, size_t ws_size,
                              hipStream_t stream)
{
    const float* V      = (const float*)d_in[0];
    const float* E      = (const float*)d_in[1];
    const float* blocks = (const float*)d_in[2];
    const float* We1    = (const float*)d_in[3];
    const float* be1    = (const float*)d_in[4];
    const float* We2    = (const float*)d_in[5];
    const float* be2    = (const float*)d_in[6];
    const float* Wn1    = (const float*)d_in[7];
    const float* bn1    = (const float*)d_in[8];
    const float* Wn2    = (const float*)d_in[9];
    const float* bn2    = (const float*)d_in[10];
    const float* w_attn = (const float*)d_in[11];
    const float* rms_w  = (const float*)d_in[12];
    const int*   edges  = (const int*)d_in[13];
    float* out = (float*)d_out;

    float* ws = (float*)d_ws;
    float* m0sum    = ws;                         // BS*N*64
    float* m1sum    = m0sum + 2097152;
    float* c0       = m1sum + 2097152;
    float* c1       = c0 + 32768;
    float* node_emb = c1 + 32768;                 // BS*N*128
    unsigned short* wbf = (unsigned short*)(node_emb + 4194304);  // 114688 bf16

    // zero accumulators (m0sum, m1sum, c0, c1)
    hipMemsetAsync(d_ws, 0, (size_t)(2097152 * 2 + 32768 * 2) * sizeof(float), stream);

    prep_weights<<<448, 256, 0, stream>>>(We1, We2, Wn1, Wn2, wbf);

    edge_kernel<<<(NBATCH * NEDGES) / TE, 256, 0, stream>>>(
        V, E, edges, wbf, be1, wbf + 49152, be2, m0sum, m1sum, c0, c1);

    node_kernel<<<(NBATCH * NNODES) / TE, 256, 0, stream>>>(
        V, m0sum, m1sum, c0, c1, wbf + 65536, bn1, wbf + 98304, bn2, node_emb);

    attn_kernel<<<(NBATCH * NNODES) / 4, 256, 0, stream>>>(
        blocks, node_emb, w_attn, rms_w, out);
}